// Round 1
// baseline (788.908 us; speedup 1.0000x reference)
//
#include <hip/hip_runtime.h>
#include <stdint.h>

// Instant-NGP hash-grid encode, 16 levels, F=2, fp32.
// One thread per point; all 16 levels unrolled (constants fold at compile time).
// Levels 0-7 dense (res^3 == size): z-corner pair is contiguous -> 4 paired gathers.
// Levels 8-15 hashed, size = 2^19 for all -> mod folds to AND.

#define NLEV 16

__global__ __launch_bounds__(256, 4) void hashgrid_fwd(
    const float* __restrict__ xyz,
    const float2* __restrict__ emb,
    const float* __restrict__ mn,
    const float* __restrict__ mx,
    float* __restrict__ out,
    int npts)
{
    constexpr int RES[16] = {16,20,25,32,40,50,64,80,101,128,161,203,256,322,406,512};
    constexpr uint32_t OFFS[17] = {0u,4096u,12096u,27721u,60489u,124489u,249489u,511633u,
                                   1023633u,1547921u,2072209u,2596497u,3120785u,3645073u,
                                   4169361u,4693649u,5217937u};
    constexpr uint32_t P1 = 2654435761u, P2 = 805459861u;

    const int b = blockIdx.x * blockDim.x + threadIdx.x;
    if (b >= npts) return;

    const float mn0 = mn[0], mn1 = mn[1], mn2 = mn[2];
    const float inv0 = 1.0f / (mx[0] - mn0);
    const float inv1 = 1.0f / (mx[1] - mn1);
    const float inv2 = 1.0f / (mx[2] - mn2);

    const float xn = (xyz[3*b+0] - mn0) * inv0;
    const float yn = (xyz[3*b+1] - mn1) * inv1;
    const float zn = (xyz[3*b+2] - mn2) * inv2;

    float o[32];

#pragma unroll
    for (int l = 0; l < NLEV; ++l) {
        const int res = RES[l];
        const uint32_t off = OFFS[l];
        const uint32_t size = OFFS[l+1] - OFFS[l];
        const float scale = (float)(res - 1);
        const float hi = (float)(res - 2);

        const float px = xn * scale, py = yn * scale, pz = zn * scale;
        const float fx = fminf(fmaxf(floorf(px), 0.0f), hi);
        const float fy = fminf(fmaxf(floorf(py), 0.0f), hi);
        const float fz = fminf(fmaxf(floorf(pz), 0.0f), hi);
        const float wx1 = px - fx, wy1 = py - fy, wz1 = pz - fz;
        const float wx0 = 1.0f - wx1, wy0 = 1.0f - wy1, wz0 = 1.0f - wz1;
        const uint32_t ix = (uint32_t)fx, iy = (uint32_t)fy, iz = (uint32_t)fz;

        float ax = 0.0f, ay = 0.0f;

        const bool dense = ((long long)res * res * res) <= (long long)size;
        if (dense) {
            const uint32_t dx = (uint32_t)(res * res);
            const uint32_t dy = (uint32_t)res;
            const uint32_t base = off + ix * dx + iy * dy + iz;
            {   // (0,0,z)
                float2 e0 = emb[base];           float2 e1 = emb[base + 1];
                float wxy = wx0 * wy0;
                ax += wxy * (wz0 * e0.x + wz1 * e1.x);
                ay += wxy * (wz0 * e0.y + wz1 * e1.y);
            }
            {   // (0,1,z)
                float2 e0 = emb[base + dy];      float2 e1 = emb[base + dy + 1];
                float wxy = wx0 * wy1;
                ax += wxy * (wz0 * e0.x + wz1 * e1.x);
                ay += wxy * (wz0 * e0.y + wz1 * e1.y);
            }
            {   // (1,0,z)
                float2 e0 = emb[base + dx];      float2 e1 = emb[base + dx + 1];
                float wxy = wx1 * wy0;
                ax += wxy * (wz0 * e0.x + wz1 * e1.x);
                ay += wxy * (wz0 * e0.y + wz1 * e1.y);
            }
            {   // (1,1,z)
                float2 e0 = emb[base + dx + dy]; float2 e1 = emb[base + dx + dy + 1];
                float wxy = wx1 * wy1;
                ax += wxy * (wz0 * e0.x + wz1 * e1.x);
                ay += wxy * (wz0 * e0.y + wz1 * e1.y);
            }
        } else {
            const uint32_t hx0 = ix,      hx1 = ix + 1u;
            const uint32_t hy0 = iy * P1, hy1 = hy0 + P1;
            const uint32_t hz0 = iz * P2, hz1 = hz0 + P2;
            const uint32_t i000 = ((hx0 ^ hy0 ^ hz0) % size) + off;
            const uint32_t i001 = ((hx0 ^ hy0 ^ hz1) % size) + off;
            const uint32_t i010 = ((hx0 ^ hy1 ^ hz0) % size) + off;
            const uint32_t i011 = ((hx0 ^ hy1 ^ hz1) % size) + off;
            const uint32_t i100 = ((hx1 ^ hy0 ^ hz0) % size) + off;
            const uint32_t i101 = ((hx1 ^ hy0 ^ hz1) % size) + off;
            const uint32_t i110 = ((hx1 ^ hy1 ^ hz0) % size) + off;
            const uint32_t i111 = ((hx1 ^ hy1 ^ hz1) % size) + off;
            float2 e;
            float w;
            e = emb[i000]; w = wx0*wy0*wz0; ax += w*e.x; ay += w*e.y;
            e = emb[i001]; w = wx0*wy0*wz1; ax += w*e.x; ay += w*e.y;
            e = emb[i010]; w = wx0*wy1*wz0; ax += w*e.x; ay += w*e.y;
            e = emb[i011]; w = wx0*wy1*wz1; ax += w*e.x; ay += w*e.y;
            e = emb[i100]; w = wx1*wy0*wz0; ax += w*e.x; ay += w*e.y;
            e = emb[i101]; w = wx1*wy0*wz1; ax += w*e.x; ay += w*e.y;
            e = emb[i110]; w = wx1*wy1*wz0; ax += w*e.x; ay += w*e.y;
            e = emb[i111]; w = wx1*wy1*wz1; ax += w*e.x; ay += w*e.y;
        }
        o[2*l]   = ax;
        o[2*l+1] = ay;
    }

    float4* ov = (float4*)(out + (size_t)b * 32);
#pragma unroll
    for (int i = 0; i < 8; ++i)
        ov[i] = make_float4(o[4*i+0], o[4*i+1], o[4*i+2], o[4*i+3]);
}

extern "C" void kernel_launch(void* const* d_in, const int* in_sizes, int n_in,
                              void* d_out, int out_size, void* d_ws, size_t ws_size,
                              hipStream_t stream) {
    const float*  xyz = (const float*)d_in[0];
    const float2* emb = (const float2*)d_in[1];
    const float*  mn  = (const float*)d_in[2];
    const float*  mx  = (const float*)d_in[3];
    float* out = (float*)d_out;

    const int npts = in_sizes[0] / 3;          // 1<<20
    const int block = 256;
    const int grid = (npts + block - 1) / block;

    hipLaunchKernelGGL(hashgrid_fwd, dim3(grid), dim3(block), 0, stream,
                       xyz, emb, mn, mx, out, npts);
}

// Round 2
// 778.725 us; speedup vs baseline: 1.0131x; 1.0131x over previous
//
#include <hip/hip_runtime.h>
#include <stdint.h>

// Instant-NGP hash-grid encode, 16 levels, F=2, fp32 — LEVEL-PHASED version.
// gridDim.y = 9 phases executed (approximately) back-to-back within one launch:
//   y == 0   : dense levels 0..7 (tables total 8.2 MB), writes 64 B contiguous/thread
//   y == 1..8: one hashed level each (table = 4 MB = per-XCD L2 size), so the
//              level's table stays L2-resident during its phase -> gather hits L2.
// All hashed levels have size 524288 = 2^19 -> modulo folds to & 0x7FFFF.

__device__ __constant__ int kRES[16] = {16,20,25,32,40,50,64,80,101,128,161,203,256,322,406,512};

__global__ __launch_bounds__(256, 8) void hashgrid_phased(
    const float* __restrict__ xyz,
    const float2* __restrict__ emb,
    const float* __restrict__ mn,
    const float* __restrict__ mx,
    float* __restrict__ out,
    int npts)
{
    constexpr uint32_t P1 = 2654435761u, P2 = 805459861u;
    constexpr uint32_t HASH_MASK = 0x7FFFFu;     // 524288 - 1
    constexpr uint32_t HASH_BASE = 1023633u;     // OFFS[8]

    const int b = blockIdx.x * blockDim.x + threadIdx.x;
    if (b >= npts) return;

    const float mn0 = mn[0], mn1 = mn[1], mn2 = mn[2];
    const float inv0 = 1.0f / (mx[0] - mn0);
    const float inv1 = 1.0f / (mx[1] - mn1);
    const float inv2 = 1.0f / (mx[2] - mn2);

    const float xn = (xyz[3*b+0] - mn0) * inv0;
    const float yn = (xyz[3*b+1] - mn1) * inv1;
    const float zn = (xyz[3*b+2] - mn2) * inv2;

    const int y = blockIdx.y;

    if (y == 0) {
        // ---------------- dense levels 0..7 ----------------
        constexpr int RES[8] = {16,20,25,32,40,50,64,80};
        constexpr uint32_t OFFS[8] = {0u,4096u,12096u,27721u,60489u,124489u,249489u,511633u};
        float o[16];
#pragma unroll
        for (int l = 0; l < 8; ++l) {
            const int res = RES[l];
            const uint32_t off = OFFS[l];
            const float scale = (float)(res - 1);
            const float hi = (float)(res - 2);

            const float px = xn * scale, py = yn * scale, pz = zn * scale;
            const float fx = fminf(fmaxf(floorf(px), 0.0f), hi);
            const float fy = fminf(fmaxf(floorf(py), 0.0f), hi);
            const float fz = fminf(fmaxf(floorf(pz), 0.0f), hi);
            const float wx1 = px - fx, wy1 = py - fy, wz1 = pz - fz;
            const float wx0 = 1.0f - wx1, wy0 = 1.0f - wy1, wz0 = 1.0f - wz1;
            const uint32_t ix = (uint32_t)fx, iy = (uint32_t)fy, iz = (uint32_t)fz;

            const uint32_t dx = (uint32_t)(res * res);
            const uint32_t dy = (uint32_t)res;
            const uint32_t base = off + ix * dx + iy * dy + iz;

            float ax = 0.0f, ay = 0.0f;
            {
                float2 e0 = emb[base];           float2 e1 = emb[base + 1];
                float wxy = wx0 * wy0;
                ax += wxy * (wz0 * e0.x + wz1 * e1.x);
                ay += wxy * (wz0 * e0.y + wz1 * e1.y);
            }
            {
                float2 e0 = emb[base + dy];      float2 e1 = emb[base + dy + 1];
                float wxy = wx0 * wy1;
                ax += wxy * (wz0 * e0.x + wz1 * e1.x);
                ay += wxy * (wz0 * e0.y + wz1 * e1.y);
            }
            {
                float2 e0 = emb[base + dx];      float2 e1 = emb[base + dx + 1];
                float wxy = wx1 * wy0;
                ax += wxy * (wz0 * e0.x + wz1 * e1.x);
                ay += wxy * (wz0 * e0.y + wz1 * e1.y);
            }
            {
                float2 e0 = emb[base + dx + dy]; float2 e1 = emb[base + dx + dy + 1];
                float wxy = wx1 * wy1;
                ax += wxy * (wz0 * e0.x + wz1 * e1.x);
                ay += wxy * (wz0 * e0.y + wz1 * e1.y);
            }
            o[2*l]   = ax;
            o[2*l+1] = ay;
        }
        float4* ov = (float4*)(out + (size_t)b * 32);
#pragma unroll
        for (int i = 0; i < 4; ++i)
            ov[i] = make_float4(o[4*i+0], o[4*i+1], o[4*i+2], o[4*i+3]);
    } else {
        // ---------------- one hashed level (8..15) ----------------
        const int l = y + 7;
        const int res = kRES[l];                        // wave-uniform scalar load
        const uint32_t off = HASH_BASE + (uint32_t)(l - 8) * 524288u;

        const float scale = (float)(res - 1);
        const float hi = (float)(res - 2);

        const float px = xn * scale, py = yn * scale, pz = zn * scale;
        const float fx = fminf(fmaxf(floorf(px), 0.0f), hi);
        const float fy = fminf(fmaxf(floorf(py), 0.0f), hi);
        const float fz = fminf(fmaxf(floorf(pz), 0.0f), hi);
        const float wx1 = px - fx, wy1 = py - fy, wz1 = pz - fz;
        const float wx0 = 1.0f - wx1, wy0 = 1.0f - wy1, wz0 = 1.0f - wz1;
        const uint32_t ix = (uint32_t)fx, iy = (uint32_t)fy, iz = (uint32_t)fz;

        const uint32_t hx0 = ix,      hx1 = ix + 1u;
        const uint32_t hy0 = iy * P1, hy1 = hy0 + P1;
        const uint32_t hz0 = iz * P2, hz1 = hz0 + P2;

        const uint32_t i000 = ((hx0 ^ hy0 ^ hz0) & HASH_MASK) + off;
        const uint32_t i001 = ((hx0 ^ hy0 ^ hz1) & HASH_MASK) + off;
        const uint32_t i010 = ((hx0 ^ hy1 ^ hz0) & HASH_MASK) + off;
        const uint32_t i011 = ((hx0 ^ hy1 ^ hz1) & HASH_MASK) + off;
        const uint32_t i100 = ((hx1 ^ hy0 ^ hz0) & HASH_MASK) + off;
        const uint32_t i101 = ((hx1 ^ hy0 ^ hz1) & HASH_MASK) + off;
        const uint32_t i110 = ((hx1 ^ hy1 ^ hz0) & HASH_MASK) + off;
        const uint32_t i111 = ((hx1 ^ hy1 ^ hz1) & HASH_MASK) + off;

        // issue all 8 gathers before consuming (compiler batches vmcnt waits)
        float2 e000 = emb[i000], e001 = emb[i001], e010 = emb[i010], e011 = emb[i011];
        float2 e100 = emb[i100], e101 = emb[i101], e110 = emb[i110], e111 = emb[i111];

        float ax, ay, w;
        w = wx0*wy0*wz0; ax  = w*e000.x; ay  = w*e000.y;
        w = wx0*wy0*wz1; ax += w*e001.x; ay += w*e001.y;
        w = wx0*wy1*wz0; ax += w*e010.x; ay += w*e010.y;
        w = wx0*wy1*wz1; ax += w*e011.x; ay += w*e011.y;
        w = wx1*wy0*wz0; ax += w*e100.x; ay += w*e100.y;
        w = wx1*wy0*wz1; ax += w*e101.x; ay += w*e101.y;
        w = wx1*wy1*wz0; ax += w*e110.x; ay += w*e110.y;
        w = wx1*wy1*wz1; ax += w*e111.x; ay += w*e111.y;

        float2* op = (float2*)(out + (size_t)b * 32 + 2 * l);
        *op = make_float2(ax, ay);
    }
}

extern "C" void kernel_launch(void* const* d_in, const int* in_sizes, int n_in,
                              void* d_out, int out_size, void* d_ws, size_t ws_size,
                              hipStream_t stream) {
    const float*  xyz = (const float*)d_in[0];
    const float2* emb = (const float2*)d_in[1];
    const float*  mn  = (const float*)d_in[2];
    const float*  mx  = (const float*)d_in[3];
    float* out = (float*)d_out;

    const int npts = in_sizes[0] / 3;          // 1<<20
    const int block = 256;
    const int grid_x = (npts + block - 1) / block;

    hipLaunchKernelGGL(hashgrid_phased, dim3(grid_x, 9), dim3(block), 0, stream,
                       xyz, emb, mn, mx, out, npts);
}